// Round 1
// baseline (304.899 us; speedup 1.0000x reference)
//
#include <hip/hip_runtime.h>
#include <hip/hip_bf16.h>

#define TEMP_INV 14.285714285714286f  // 1/0.07

typedef __attribute__((ext_vector_type(8))) short bf16x8;
typedef __attribute__((ext_vector_type(4))) float f32x4;

// ---------------- row L2-normalize -> bf16 ----------------
// one block (256 thr) per row; D assumed 512 (2 floats/thread)
__global__ void norm_k(const float* __restrict__ feat, ushort* __restrict__ fbf, int D) {
  const int row = blockIdx.x;
  const int t = threadIdx.x;
  const float2* fr = (const float2*)(feat + (size_t)row * D);
  float2 v = fr[t];
  float ss = v.x * v.x + v.y * v.y;
  #pragma unroll
  for (int off = 32; off; off >>= 1) ss += __shfl_xor(ss, off, 64);
  __shared__ float ws4[4];
  if ((t & 63) == 0) ws4[t >> 6] = ss;
  __syncthreads();
  float tot = ws4[0] + ws4[1] + ws4[2] + ws4[3];
  float inv = 1.0f / fmaxf(sqrtf(tot), 1e-12f);
  __hip_bfloat16 a = __float2bfloat16(v.x * inv);
  __hip_bfloat16 b = __float2bfloat16(v.y * inv);
  ushort2 o;
  o.x = *(ushort*)&a;
  o.y = *(ushort*)&b;
  ((ushort2*)(fbf + (size_t)row * D))[t] = o;
}

// ---------------- group labels + histogram ----------------
__global__ void label_k(const int* __restrict__ labels, const int* __restrict__ kptr,
                        int* __restrict__ glab, int* __restrict__ cnt, int N) {
  const int k = *kptr;
  const int B = N / k;
  __shared__ int h[64];
  const int t = threadIdx.x;
  if (t < 64) h[t] = 0;
  __syncthreads();
  for (int b = t; b < B; b += blockDim.x) {
    int lb = labels[(size_t)b * k];
    if (lb >= 0 && lb < 64) atomicAdd(&h[lb], 1);
  }
  __syncthreads();
  if (t < 64) cnt[t] = h[t];
  for (int i = t; i < N; i += blockDim.x) glab[i] = labels[(size_t)(i / k) * k];
}

// ---------------- fused GEMM + masked-softmax-stats epilogue ----------------
// 128x128 tile, 4 waves, each wave 64x64 via 4x4 grid of 16x16x32 bf16 MFMA
__global__ __launch_bounds__(256) void gemm_k(const ushort* __restrict__ fbf,
                                              const int* __restrict__ glab,
                                              float* __restrict__ rowS,
                                              float* __restrict__ rowP,
                                              int N, int D) {
  __shared__ ushort As[128][32];
  __shared__ ushort Bs[128][32];
  const int t = threadIdx.x;
  const int lane = t & 63;
  const int wid = t >> 6;
  const int wrow = wid >> 1, wcol = wid & 1;
  const int quad = lane >> 4, l15 = lane & 15;
  const int i0 = blockIdx.y * 128, j0 = blockIdx.x * 128;

  f32x4 acc[4][4];
  #pragma unroll
  for (int mi = 0; mi < 4; mi++)
    #pragma unroll
    for (int ni = 0; ni < 4; ni++) {
      f32x4 z = {0.f, 0.f, 0.f, 0.f};
      acc[mi][ni] = z;
    }

  const int lr = t >> 2;        // 0..63
  const int lc = (t & 3) * 8;   // bf16 offset 0,8,16,24

  for (int kb = 0; kb < D; kb += 32) {
    __syncthreads();
    *(uint4*)&As[lr][lc]      = *(const uint4*)(fbf + (size_t)(i0 + lr) * D + kb + lc);
    *(uint4*)&As[64 + lr][lc] = *(const uint4*)(fbf + (size_t)(i0 + 64 + lr) * D + kb + lc);
    *(uint4*)&Bs[lr][lc]      = *(const uint4*)(fbf + (size_t)(j0 + lr) * D + kb + lc);
    *(uint4*)&Bs[64 + lr][lc] = *(const uint4*)(fbf + (size_t)(j0 + 64 + lr) * D + kb + lc);
    __syncthreads();

    bf16x8 a[4], b[4];
    const int ko = quad * 8;
    #pragma unroll
    for (int mi = 0; mi < 4; mi++) a[mi] = *(const bf16x8*)&As[wrow * 64 + mi * 16 + l15][ko];
    #pragma unroll
    for (int ni = 0; ni < 4; ni++) b[ni] = *(const bf16x8*)&Bs[wcol * 64 + ni * 16 + l15][ko];
    #pragma unroll
    for (int mi = 0; mi < 4; mi++)
      #pragma unroll
      for (int ni = 0; ni < 4; ni++)
        acc[mi][ni] = __builtin_amdgcn_mfma_f32_16x16x32_bf16(a[mi], b[ni], acc[mi][ni], 0, 0, 0);
  }

  // epilogue: per-element exp + mask, 16-lane row reduce, atomics
  const int colbase = j0 + wcol * 64 + l15;
  int clab[4];
  #pragma unroll
  for (int ni = 0; ni < 4; ni++) clab[ni] = glab[colbase + ni * 16];

  #pragma unroll
  for (int mi = 0; mi < 4; mi++) {
    #pragma unroll
    for (int r = 0; r < 4; r++) {
      const int row = i0 + wrow * 64 + mi * 16 + quad * 4 + r;
      const int rlab = glab[row];
      float Ssum = 0.f, Psum = 0.f;
      #pragma unroll
      for (int ni = 0; ni < 4; ni++) {
        const int col = colbase + ni * 16;
        const float val = acc[mi][ni][r];
        const float lg = fmaf(val, TEMP_INV, -TEMP_INV);  // (sim - 1)/T
        const bool diag = (row == col);
        const float e = diag ? 0.f : __expf(lg);
        Ssum += e;
        if (!diag && rlab == clab[ni]) Psum += lg;
      }
      #pragma unroll
      for (int off = 8; off; off >>= 1) {
        Ssum += __shfl_xor(Ssum, off, 64);
        Psum += __shfl_xor(Psum, off, 64);
      }
      if (l15 == 0) {
        atomicAdd(&rowS[row], Ssum);
        atomicAdd(&rowP[row], Psum);
      }
    }
  }
}

// ---------------- final loss reduction ----------------
__global__ void loss_k(const float* __restrict__ rowS, const float* __restrict__ rowP,
                       const int* __restrict__ glab, const int* __restrict__ cnt,
                       const int* __restrict__ kptr, float* __restrict__ out, int N) {
  const int k = *kptr;
  const int t = threadIdx.x;
  float lsum = 0.f, vsum = 0.f;
  for (int i = t; i < N; i += blockDim.x) {
    const int np = cnt[glab[i]] * k - 1;
    if (np > 0) {
      const float S = rowS[i] + 1e-8f;
      const float P = rowP[i];
      const float mlp = (P - (float)np * logf(S)) / (float)np;
      lsum += -mlp;  // -(T/BASE_T) = -1
      vsum += 1.f;
    }
  }
  #pragma unroll
  for (int off = 32; off; off >>= 1) {
    lsum += __shfl_xor(lsum, off, 64);
    vsum += __shfl_xor(vsum, off, 64);
  }
  __shared__ float sl[4], sv[4];
  if ((t & 63) == 0) { sl[t >> 6] = lsum; sv[t >> 6] = vsum; }
  __syncthreads();
  if (t == 0) {
    float L = sl[0] + sl[1] + sl[2] + sl[3];
    float V = sv[0] + sv[1] + sv[2] + sv[3];
    out[0] = L / fmaxf(V, 1.f);
  }
}

extern "C" void kernel_launch(void* const* d_in, const int* in_sizes, int n_in,
                              void* d_out, int out_size, void* d_ws, size_t ws_size,
                              hipStream_t stream) {
  const float* feat = (const float*)d_in[0];
  const int* labels = (const int*)d_in[1];
  const int* kptr   = (const int*)d_in[2];
  const int N = in_sizes[1];
  const int D = in_sizes[0] / N;  // 512

  char* ws = (char*)d_ws;
  ushort* fbf = (ushort*)ws;
  size_t off = (size_t)N * D * sizeof(ushort);
  float* rowS = (float*)(ws + off); off += (size_t)N * sizeof(float);
  float* rowP = (float*)(ws + off); off += (size_t)N * sizeof(float);
  int* glab   = (int*)(ws + off);   off += (size_t)N * sizeof(int);
  int* cnt    = (int*)(ws + off);   off += 64 * sizeof(int);

  // rowS and rowP are contiguous: one memset
  hipMemsetAsync(rowS, 0, 2 * (size_t)N * sizeof(float), stream);

  norm_k<<<N, 256, 0, stream>>>(feat, fbf, D);
  label_k<<<1, 256, 0, stream>>>(labels, kptr, glab, cnt, N);
  dim3 grid(N / 128, N / 128);
  gemm_k<<<grid, 256, 0, stream>>>(fbf, glab, rowS, rowP, N, D);
  loss_k<<<1, 256, 0, stream>>>(rowS, rowP, glab, cnt, kptr, (float*)d_out, N);
}